// Round 14
// baseline (35.639 us; speedup 1.0000x reference)
//
#include <hip/hip_runtime.h>

// Sinkhorn OT loss, one 64-lane wave per frame, zero barriers, SINGLE kernel.
// N=2048 frames, A=64 osc, B=513 bins, eps=0.01 -> beta=100*log2(e)*15.625.
// ONE Sinkhorn iteration: u1 closed-form (V==0) -> moment-fused {v1, pi*cost}
// (R11/R12/R13: 3-iter, 2-iter, 1-iter all EXACTLY equal the 5-iter reference
// at fp32 -- beta=2254 locks the transport after the first round-trip).
// Final mean fused via device-scope ATOMICS ONLY (no __threadfence -- R7
// showed the fence costs ~60us as buffer_wbl2 per block): publish via
// atomicExch (coherent point), vmcnt(0), arrival counter (mod-2048, poison-
// proof); last arriver reads back via atomicAdd(p,0) RMWs in fixed index
// order -> bit-deterministic mean, no spin, no deadlock.

#define NN 2048
#define NEGF (-1.0e30f)
#define DEAD 3.0e12f
#define BETA 2254.2110013890053f           // 100*log2(e)*15.625
#define INVB 4.4361353928294959e-4f        // 1/BETA
#define SCALE 15.625f

static __device__ __forceinline__ float EXP2(float x){ return __builtin_amdgcn_exp2f(x); }
static __device__ __forceinline__ float LOG2(float x){ return __builtin_amdgcn_logf(x); }
static __device__ __forceinline__ float lse1(float x, float y){
    float mx = fmaxf(x, y);
    return mx + LOG2(1.0f + EXP2(-fabsf(x - y)));
}
static __device__ __forceinline__ float wave_sum(float v){
#pragma unroll
    for (int o = 32; o > 0; o >>= 1) v += __shfl_xor(v, o);
    return v;
}
template<int C> static __device__ __forceinline__ float dppN(float x){   // old = NEGF
    return __int_as_float(__builtin_amdgcn_update_dpp(
        __float_as_int(NEGF), __float_as_int(x), C, 0xf, 0xf, false));
}
template<int C> static __device__ __forceinline__ float dpp0(float x){   // old = 0
    return __int_as_float(__builtin_amdgcn_update_dpp(
        0, __float_as_int(x), C, 0xf, 0xf, false));
}
// full-wave reversal: x[63-l] = row_mirror (lane^15, pure DPP) then lane^48.
static __device__ __forceinline__ float revw(float x, int l){
    float m = dpp0<0x140>(x);
    return __shfl_xor(m, 48);
}
static __device__ __forceinline__ float bperm(int a4, float v){
    return __int_as_float(__builtin_amdgcn_ds_bpermute(a4, __float_as_int(v)));
}

// moment-augmented scan level (log-weight F, E[distance] M)
#define MLVL(CTRL, G, F, M) {                                          \
    float o_ = dppN<CTRL>(F); float om_ = dpp0<CTRL>(M);               \
    float xo_ = o_ - (G); float Lc_ = lse1(xo_, F);                    \
    M = fmaf(EXP2(xo_ - Lc_), fmaf((G), INVB, om_), EXP2(F - Lc_)*M);  \
    F = Lc_; }

__global__ __launch_bounds__(64, 2) void sink_fused_kernel(
    const float* __restrict__ freqs, const float* __restrict__ amps,
    const float* __restrict__ spec, float* __restrict__ ws,
    unsigned* __restrict__ cnt, float* __restrict__ out)
{
    const int n = blockIdx.x, l = threadIdx.x;
    __shared__ __align__(16) float tsr[64];
    __shared__ float tp[66];
    __shared__ float smu[64];

    // ---- oscillator inputs ----
    float traw = freqs[n*64 + l] * (1.0f/15.625f);
    float av   = amps [n*64 + l];
    av = fminf(fmaxf(av, 0.0f), 1e9f) + 1e-9f;
    float Sa   = wave_sum(av);
    float Mraw = LOG2(av) - LOG2(Sa);
    tsr[l] = traw;
    if (l == 0) { tp[0] = 0.0f; tp[65] = 20000.0f; }

    // ---- spec -> Nu ----
    const float* sp = spec + n*513;
    float sv[8], part = 0.0f;
#pragma unroll
    for (int i = 0; i < 8; ++i) {
        float x = sp[8*l + i];
        x = fminf(fmaxf(x, 0.0f), 1e9f) + 1e-9f;
        sv[i] = x; part += x;
    }
    float s512 = 0.0f;
    if (l == 63) { s512 = fminf(fmaxf(sp[512], 0.0f), 1e9f) + 1e-9f; part += s512; }
    float lsn = LOG2(wave_sum(part));
    float Nu8[8];
#pragma unroll
    for (int i = 0; i < 8; ++i) Nu8[i] = LOG2(sv[i]) - lsn;
    float Nu512 = (l == 63) ? (LOG2(s512) - lsn) : NEGF;

    // ---- rank sort ----
    {
        int r = 0;
        const float4* t4 = (const float4*)tsr;
#pragma unroll
        for (int q = 0; q < 16; ++q) {
            float4 tt = t4[q]; int j = 4*q;
            r += (tt.x < traw) || (tt.x == traw && (j+0) < l);
            r += (tt.y < traw) || (tt.y == traw && (j+1) < l);
            r += (tt.z < traw) || (tt.z == traw && (j+2) < l);
            r += (tt.w < traw) || (tt.w == traw && (j+3) < l);
        }
        tp[1 + r] = traw;
        smu[r]    = Mraw;
    }
    float t  = tp[1 + l];
    float Mu = smu[l];

    // ---- moment-scan decay registers ----
    float t15 = __shfl(t, 15), t31 = __shfl(t, 31), t47 = __shfl(t, 47);
    float t16 = __shfl(t, 16), t32 = __shfl(t, 32), t48 = __shfl(t, 48);
    float trev = revw(t, l);
    float gu[4], gm[4];
#pragma unroll
    for (int k = 0; k < 4; ++k) {
        int d = 1 << k;
        gu[k] = BETA*(t - __shfl_up(t, d));          // row-boundary lanes: DPP NEGF kills
        gm[k] = BETA*(__shfl_up(trev, d) - trev);
    }
    bool r1 = (l >= 16 && l < 32), r3 = (l >= 48), h1 = (l >= 32);
    float gu15 = r1 ? BETA*(t - t15)    : r3 ? BETA*(t - t47)    : DEAD;
    float gu31 = h1 ? BETA*(t - t31)    : DEAD;
    float gm15 = r1 ? BETA*(t48 - trev) : r3 ? BETA*(t16 - trev) : DEAD;
    float gm31 = h1 ? BETA*(t32 - trev) : DEAD;

    // ---- per-owned-bin statics (binary search over sorted tp) ----
    int aL[8], aRm[8]; float dl[8], dr[8];
#pragma unroll
    for (int i = 0; i < 8; ++i) {
        float bf = (float)(8*l + i);
        int lo = 0, hi = 65;
#pragma unroll
        for (int s = 0; s < 7; ++s) {
            int mid = (lo + hi) >> 1;
            bool le = (tp[mid] <= bf);
            lo = le ? mid : lo; hi = le ? hi : mid;
        }
        aL[i]  = (lo - 1) << 2;                      // P lane for osc lo-1 (0-based)
        dl[i]  = (lo == 0)  ? DEAD : BETA*(bf - tp[lo]);
        aRm[i] = (63 - lo) << 2;                     // mirror-S lane for osc lo (0-based)
        dr[i]  = (lo == 64) ? DEAD : BETA*(tp[lo + 1] - bf);
    }
    float dl512 = BETA*(512.0f - tp[64]);

    // ---- u1: closed form (V == 0) ----
    int b0 = (int)t; if (b0 > 511) b0 = 511;
    float fr = t - (float)b0;
    float U = Mu - lse1(-BETA*fr, -BETA*(1.0f - fr));

    // ---- final: moment-augmented scans of u1 + fused {v1, pi*cost} ----
    float FL = U, ML = 0.0f;
    MLVL(0x111, gu[0], FL, ML) MLVL(0x112, gu[1], FL, ML)
    MLVL(0x114, gu[2], FL, ML) MLVL(0x118, gu[3], FL, ML)
    MLVL(0x142, gu15,  FL, ML) MLVL(0x143, gu31,  FL, ML)
    float FRm = revw(U, l), MRm = 0.0f;
    MLVL(0x111, gm[0], FRm, MRm) MLVL(0x112, gm[1], FRm, MRm)
    MLVL(0x114, gm[2], FRm, MRm) MLVL(0x118, gm[3], FRm, MRm)
    MLVL(0x142, gm15,  FRm, MRm) MLVL(0x143, gm31,  FRm, MRm)

    float acc = 0.0f;
#pragma unroll
    for (int i = 0; i < 8; ++i) {
        float EL = bperm(aL[i], FL) - dl[i];
        float ER = bperm(aRm[i], FRm) - dr[i];
        float Vn = Nu8[i] - lse1(EL, ER);
        float mL = bperm(aL[i], ML);
        float mR = bperm(aRm[i], MRm);
        acc += EXP2(Vn + EL) * fmaf(dl[i], INVB, mL)
             + EXP2(Vn + ER) * fmaf(dr[i], INVB, mR);
    }
    float ml512 = bperm(63 << 2, ML);
    if (l == 63) acc += EXP2(Nu512) * fmaf(dl512, INVB, ml512);

    acc = wave_sum(acc) * SCALE;

    // ---- fused deterministic mean: atomics only, NO fences ----
    // publish (device-coherent point, distinct addresses -> no contention)
    float oldv = 0.0f;
    if (l == 0) oldv = atomicExch(&ws[n], acc);
    asm volatile("" :: "v"(oldv));                    // consume: forces vmcnt wait chain
    asm volatile("s_waitcnt vmcnt(0)" ::: "memory");  // exch complete before counter
    unsigned old = 0;
    if (l == 0) old = atomicAdd(cnt, 1u);
    old = (unsigned)__shfl((int)old, 0);
    if ((old & 2047u) == 2047u) {                     // exactly one winner per 2048 arrivals
        // all 2048 exchs are complete (each preceded its counter increment);
        // read back through the coherent point via RMW adds of 0.
        float s32[32];
#pragma unroll
        for (int k = 0; k < 32; ++k)
            s32[k] = atomicAdd(&ws[l + 64*k], 0.0f);  // independent -> pipelined
        float s = 0.0f;
#pragma unroll
        for (int k = 0; k < 32; ++k) s += s32[k];     // fixed order -> deterministic
        s = wave_sum(s);
        if (l == 0) out[0] = s * (1.0f/2048.0f);
    }
}

extern "C" void kernel_launch(void* const* d_in, const int* in_sizes, int n_in,
                              void* d_out, int out_size, void* d_ws, size_t ws_size,
                              hipStream_t stream) {
    const float* freqs = (const float*)d_in[0];  // (2048,64)
    const float* amps  = (const float*)d_in[1];  // (2048,64)
    const float* spec  = (const float*)d_in[2];  // (2048,513)
    float*    ws  = (float*)d_ws;                // 2048 floats
    unsigned* cnt = (unsigned*)(ws + NN);        // arrival counter (mod-2048, no reset)

    sink_fused_kernel<<<NN, 64, 0, stream>>>(freqs, amps, spec, ws, cnt, (float*)d_out);
}

// Round 15
// 14.841 us; speedup vs baseline: 2.4015x; 2.4015x over previous
//
#include <hip/hip_runtime.h>

// Sinkhorn OT loss, one 64-lane wave per frame, zero barriers.
// N=2048 frames, A=64 osc, B=513 bins, eps=0.01 -> beta=100*log2(e)*15.625.
// ONE Sinkhorn iteration: u1 closed-form (V==0) -> moment-fused final
// {v1, transport}. R11/R12/R13: 3-iter, 2-iter, 1-iter all EXACTLY equal the
// 5-iter reference at fp32 (beta=2254 locks transport after one round-trip).
// Two-kernel structure is FINAL: R7 (fence fusion, 85us) and R14 (atomic-
// counter fusion, 36us) both proved grid-wide completion detection costs
// >=20us on MI355X (L2 writeback / counter cacheline serialization); the
// 1-block reduce kernel's launch (~2-4us) is strictly cheaper.

#define NN 2048
#define NEGF (-1.0e30f)
#define DEAD 3.0e12f
#define BETA 2254.2110013890053f           // 100*log2(e)*15.625
#define INVB 4.4361353928294959e-4f        // 1/BETA
#define SCALE 15.625f

static __device__ __forceinline__ float EXP2(float x){ return __builtin_amdgcn_exp2f(x); }
static __device__ __forceinline__ float LOG2(float x){ return __builtin_amdgcn_logf(x); }
static __device__ __forceinline__ float lse1(float x, float y){
    float mx = fmaxf(x, y);
    return mx + LOG2(1.0f + EXP2(-fabsf(x - y)));
}
static __device__ __forceinline__ float wave_sum(float v){
#pragma unroll
    for (int o = 32; o > 0; o >>= 1) v += __shfl_xor(v, o);
    return v;
}
template<int C> static __device__ __forceinline__ float dppN(float x){   // old = NEGF
    return __int_as_float(__builtin_amdgcn_update_dpp(
        __float_as_int(NEGF), __float_as_int(x), C, 0xf, 0xf, false));
}
template<int C> static __device__ __forceinline__ float dpp0(float x){   // old = 0
    return __int_as_float(__builtin_amdgcn_update_dpp(
        0, __float_as_int(x), C, 0xf, 0xf, false));
}
// full-wave reversal: x[63-l] = row_mirror (lane^15, pure DPP) then lane^48.
static __device__ __forceinline__ float revw(float x, int l){
    float m = dpp0<0x140>(x);
    return __shfl_xor(m, 48);
}
static __device__ __forceinline__ float bperm(int a4, float v){
    return __int_as_float(__builtin_amdgcn_ds_bpermute(a4, __float_as_int(v)));
}

// moment-augmented scan level (log-weight F, E[distance] M)
#define MLVL(CTRL, G, F, M) {                                          \
    float o_ = dppN<CTRL>(F); float om_ = dpp0<CTRL>(M);               \
    float xo_ = o_ - (G); float Lc_ = lse1(xo_, F);                    \
    M = fmaf(EXP2(xo_ - Lc_), fmaf((G), INVB, om_), EXP2(F - Lc_)*M);  \
    F = Lc_; }

__global__ __launch_bounds__(64, 2) void sink1_kernel(
    const float* __restrict__ freqs, const float* __restrict__ amps,
    const float* __restrict__ spec, float* __restrict__ ws)
{
    const int n = blockIdx.x, l = threadIdx.x;
    __shared__ __align__(16) float tsr[64];
    __shared__ float tp[66];
    __shared__ float smu[64];

    // ---- oscillator inputs ----
    float traw = freqs[n*64 + l] * (1.0f/15.625f);
    float av   = amps [n*64 + l];
    av = fminf(fmaxf(av, 0.0f), 1e9f) + 1e-9f;
    float Sa   = wave_sum(av);
    float Mraw = LOG2(av) - LOG2(Sa);
    tsr[l] = traw;
    if (l == 0) { tp[0] = 0.0f; tp[65] = 20000.0f; }

    // ---- spec -> Nu ----
    const float* sp = spec + n*513;
    float sv[8], part = 0.0f;
#pragma unroll
    for (int i = 0; i < 8; ++i) {
        float x = sp[8*l + i];
        x = fminf(fmaxf(x, 0.0f), 1e9f) + 1e-9f;
        sv[i] = x; part += x;
    }
    float s512 = 0.0f;
    if (l == 63) { s512 = fminf(fmaxf(sp[512], 0.0f), 1e9f) + 1e-9f; part += s512; }
    float lsn = LOG2(wave_sum(part));
    float Nu8[8];
#pragma unroll
    for (int i = 0; i < 8; ++i) Nu8[i] = LOG2(sv[i]) - lsn;
    float Nu512 = (l == 63) ? (LOG2(s512) - lsn) : NEGF;

    // ---- rank sort ----
    {
        int r = 0;
        const float4* t4 = (const float4*)tsr;
#pragma unroll
        for (int q = 0; q < 16; ++q) {
            float4 tt = t4[q]; int j = 4*q;
            r += (tt.x < traw) || (tt.x == traw && (j+0) < l);
            r += (tt.y < traw) || (tt.y == traw && (j+1) < l);
            r += (tt.z < traw) || (tt.z == traw && (j+2) < l);
            r += (tt.w < traw) || (tt.w == traw && (j+3) < l);
        }
        tp[1 + r] = traw;
        smu[r]    = Mraw;
    }
    float t  = tp[1 + l];
    float Mu = smu[l];

    // ---- moment-scan decay registers ----
    float t15 = __shfl(t, 15), t31 = __shfl(t, 31), t47 = __shfl(t, 47);
    float t16 = __shfl(t, 16), t32 = __shfl(t, 32), t48 = __shfl(t, 48);
    float trev = revw(t, l);
    float gu[4], gm[4];
#pragma unroll
    for (int k = 0; k < 4; ++k) {
        int d = 1 << k;
        gu[k] = BETA*(t - __shfl_up(t, d));          // row-boundary lanes: DPP NEGF kills
        gm[k] = BETA*(__shfl_up(trev, d) - trev);
    }
    bool r1 = (l >= 16 && l < 32), r3 = (l >= 48), h1 = (l >= 32);
    float gu15 = r1 ? BETA*(t - t15)    : r3 ? BETA*(t - t47)    : DEAD;
    float gu31 = h1 ? BETA*(t - t31)    : DEAD;
    float gm15 = r1 ? BETA*(t48 - trev) : r3 ? BETA*(t16 - trev) : DEAD;
    float gm31 = h1 ? BETA*(t32 - trev) : DEAD;

    // ---- per-owned-bin statics (binary search over sorted tp) ----
    int aL[8], aRm[8]; float dl[8], dr[8];
#pragma unroll
    for (int i = 0; i < 8; ++i) {
        float bf = (float)(8*l + i);
        int lo = 0, hi = 65;
#pragma unroll
        for (int s = 0; s < 7; ++s) {
            int mid = (lo + hi) >> 1;
            bool le = (tp[mid] <= bf);
            lo = le ? mid : lo; hi = le ? hi : mid;
        }
        aL[i]  = (lo - 1) << 2;                      // P lane for osc lo-1 (0-based)
        dl[i]  = (lo == 0)  ? DEAD : BETA*(bf - tp[lo]);
        aRm[i] = (63 - lo) << 2;                     // mirror-S lane for osc lo (0-based)
        dr[i]  = (lo == 64) ? DEAD : BETA*(tp[lo + 1] - bf);
    }
    float dl512 = BETA*(512.0f - tp[64]);

    // ---- u1: closed form (V == 0) ----
    int b0 = (int)t; if (b0 > 511) b0 = 511;
    float fr = t - (float)b0;
    float U = Mu - lse1(-BETA*fr, -BETA*(1.0f - fr));

    // ---- final: moment-augmented scans of u1 + fused {v1, pi*cost} ----
    float FL = U, ML = 0.0f;
    MLVL(0x111, gu[0], FL, ML) MLVL(0x112, gu[1], FL, ML)
    MLVL(0x114, gu[2], FL, ML) MLVL(0x118, gu[3], FL, ML)
    MLVL(0x142, gu15,  FL, ML) MLVL(0x143, gu31,  FL, ML)
    float FRm = revw(U, l), MRm = 0.0f;
    MLVL(0x111, gm[0], FRm, MRm) MLVL(0x112, gm[1], FRm, MRm)
    MLVL(0x114, gm[2], FRm, MRm) MLVL(0x118, gm[3], FRm, MRm)
    MLVL(0x142, gm15,  FRm, MRm) MLVL(0x143, gm31,  FRm, MRm)

    float acc = 0.0f;
#pragma unroll
    for (int i = 0; i < 8; ++i) {
        float EL = bperm(aL[i], FL) - dl[i];
        float ER = bperm(aRm[i], FRm) - dr[i];
        float Vn = Nu8[i] - lse1(EL, ER);
        float mL = bperm(aL[i], ML);
        float mR = bperm(aRm[i], MRm);
        acc += EXP2(Vn + EL) * fmaf(dl[i], INVB, mL)
             + EXP2(Vn + ER) * fmaf(dr[i], INVB, mR);
    }
    float ml512 = bperm(63 << 2, ML);
    if (l == 63) acc += EXP2(Nu512) * fmaf(dl512, INVB, ml512);

    acc = wave_sum(acc) * SCALE;
    if (l == 0) ws[n] = acc;
}

// Deterministic second-stage reduction (no atomics -> bit-stable across replays).
__global__ __launch_bounds__(256) void reduce_kernel(
    const float* __restrict__ ws, float* __restrict__ out)
{
    __shared__ float sm[4];
    int tid = threadIdx.x;
    const float4* w4 = (const float4*)ws;
    float4 a = w4[tid], b = w4[tid + 256];
    float s = (a.x + a.y + a.z + a.w) + (b.x + b.y + b.z + b.w);
    s = wave_sum(s);
    if ((tid & 63) == 0) sm[tid >> 6] = s;
    __syncthreads();
    if (tid == 0) out[0] = (sm[0] + sm[1] + sm[2] + sm[3]) * (1.0f / 2048.0f);
}

extern "C" void kernel_launch(void* const* d_in, const int* in_sizes, int n_in,
                              void* d_out, int out_size, void* d_ws, size_t ws_size,
                              hipStream_t stream) {
    const float* freqs = (const float*)d_in[0];  // (2048,64)
    const float* amps  = (const float*)d_in[1];  // (2048,64)
    const float* spec  = (const float*)d_in[2];  // (2048,513)
    float* ws = (float*)d_ws;                    // 2048 floats

    sink1_kernel<<<NN, 64, 0, stream>>>(freqs, amps, spec, ws);
    reduce_kernel<<<1, 256, 0, stream>>>(ws, (float*)d_out);
}